// Round 4
// baseline (282.953 us; speedup 1.0000x reference)
//
#include <hip/hip_runtime.h>

// 7x7 conv, stride 1, pad 3, on 64 x 512 x 512 fp32 (single channel).
// out[n,y,x] = sum_{ky,kx} x[n, y+ky-3, x+kx-3] * w[ky,kx]
//
// LDS-free streaming design. Each thread computes a 4(x) x 8(y) output
// patch, reading 14 input rows x 3 CONTIGUOUS float4 (cols ox-4..ox+7)
// straight from global; L1/L2 serve the overlap. No barrier, no LDS.

#define IMG_W 512
#define IMG_H 512
#define NIMG  64
#define ROWS  8       // output rows per thread
#define HALO  3

__global__ __launch_bounds__(256, 4) void conv7x7_kernel(
    const float* __restrict__ x,
    const float* __restrict__ wgt,
    float* __restrict__ out)
{
    const int tid = threadIdx.x;
    // 128 threads across x (128*4 = 512 = full row), 2 thread-rows per block.
    const int ox = (tid & 127) * 4;
    const int ty = tid >> 7;
    const int oy = (blockIdx.x * 2 + ty) * ROWS;
    const int n  = blockIdx.y;

    const float* img = x + (size_t)n * (IMG_W * IMG_H);

    // weights are wave-uniform -> SGPRs
    float w[49];
    #pragma unroll
    for (int i = 0; i < 49; ++i) w[i] = wgt[i];

    // x-border predicates (all-or-nothing per aligned float4):
    // left  f4 covers cols [ox-4, ox)   -> OOB only when ox == 0
    // right f4 covers cols [ox+4, ox+8) -> OOB only when ox == 508
    const bool lval = (ox != 0);
    const bool rval = (ox + 7 < IMG_W);

    float acc[ROWS][4] = {};
    const float4 z4 = make_float4(0.f, 0.f, 0.f, 0.f);

    #pragma unroll
    for (int r = 0; r < ROWS + 2 * HALO; ++r) {
        const int gy = oy - HALO + r;
        const bool yv = (unsigned)gy < IMG_H;
        const float* rp = &img[(size_t)gy * IMG_W + ox];
        const float4 a  = (yv && lval) ? *(const float4*)(rp - 4) : z4;
        const float4 b  = yv           ? *(const float4*)(rp)     : z4;
        const float4 c4 = (yv && rval) ? *(const float4*)(rp + 4) : z4;
        // row[t] holds input col ox - 4 + t (t = 0..11, contiguous).
        // Output col ox+c, tap kx needs col ox+c+kx-3 -> t = c + kx + 1.
        const float row[12] = { a.x, a.y, a.z, a.w,
                                b.x, b.y, b.z, b.w,
                                c4.x, c4.y, c4.z, c4.w };
        #pragma unroll
        for (int j = 0; j < ROWS; ++j) {
            const int ky = r - j;
            if (ky >= 0 && ky < 7) {
                #pragma unroll
                for (int kx = 0; kx < 7; ++kx) {
                    const float wv = w[ky * 7 + kx];
                    #pragma unroll
                    for (int c = 0; c < 4; ++c)
                        acc[j][c] = fmaf(row[c + kx + 1], wv, acc[j][c]);
                }
            }
        }
    }

    float* o = out + (size_t)n * (IMG_W * IMG_H);
    #pragma unroll
    for (int j = 0; j < ROWS; ++j) {
        float4 v = make_float4(acc[j][0], acc[j][1], acc[j][2], acc[j][3]);
        *(float4*)&o[(size_t)(oy + j) * IMG_W + ox] = v;
    }
}

extern "C" void kernel_launch(void* const* d_in, const int* in_sizes, int n_in,
                              void* d_out, int out_size, void* d_ws, size_t ws_size,
                              hipStream_t stream)
{
    const float* x   = (const float*)d_in[0];
    const float* wgt = (const float*)d_in[1];
    float* out       = (float*)d_out;

    // grid.x: 512 rows / (2 thread-rows * 8 rows) = 32 y-strips; grid.y: images
    dim3 grid(IMG_H / (2 * ROWS), NIMG, 1);
    conv7x7_kernel<<<grid, 256, 0, stream>>>(x, wgt, out);
}

// Round 5
// 129.832 us; speedup vs baseline: 2.1794x; 2.1794x over previous
//
#include <hip/hip_runtime.h>

// 7x7 conv, stride 1, pad 3, on 64 x 512 x 512 fp32 (single channel).
// out[n,y,x] = sum_{ky,kx} x[n, y+ky-3, x+kx-3] * w[ky,kx]
//
// R4: LDS-tiled (dedup for HBM) with SMALL LDS footprint (23 KB) so ~7 blocks
// co-reside per CU; cross-block phase overlap hides the stage-barrier drain
// that limited R1 (40 KB -> only 4 blocks/CU).

#define IMG_W 512
#define IMG_H 512
#define NIMG  64
#define TW    256            // output tile width per block
#define TH    16             // output tile height per block
#define HALO  3
// LDS col c <-> global x = bx - 4 + c (left halo padded 3->4 => 16B alignment
// for both global float4 loads and ds_read_b128).
#define LDS_W 264            // covers x in [bx-4, bx+260); 66 float4 per row
#define LDS_H (TH + 2*HALO)  // 22
#define NF4   (LDS_W / 4)    // 66

__global__ __launch_bounds__(256, 4) void conv7x7_kernel(
    const float* __restrict__ x,
    const float* __restrict__ wgt,
    float* __restrict__ out)
{
    __shared__ float tile[LDS_H * LDS_W];   // 23,232 B

    const int tid = threadIdx.x;
    const int bx  = blockIdx.x * TW;
    const int by  = blockIdx.y * TH;
    const int n   = blockIdx.z;

    const float* img = x + (size_t)n * (IMG_W * IMG_H);

    // ---- stage tile: guarded, 16B-aligned float4 only ----
    for (int i = tid; i < LDS_H * NF4; i += 256) {
        const int r  = i / NF4;
        const int c4 = i - r * NF4;
        const int gy = by - HALO + r;
        const int gx = bx - 4 + c4 * 4;
        float4 v = make_float4(0.f, 0.f, 0.f, 0.f);
        if ((unsigned)gy < IMG_H && (unsigned)gx < IMG_W)
            v = *(const float4*)&img[gy * IMG_W + gx];
        *(float4*)&tile[r * LDS_W + c4 * 4] = v;
    }

    // ---- weights: wave-uniform -> SGPRs ----
    float w[49];
    #pragma unroll
    for (int i = 0; i < 49; ++i) w[i] = wgt[i];

    __syncthreads();

    // ---- compute: 4x x 4y outputs per thread, sliding over 10 LDS rows ----
    const int tx = tid & 63;   // 64 threads across x
    const int ty = tid >> 6;   // 4 thread-rows
    const int lx = tx * 4;     // output x within tile == aligned LDS col base
    const int rbase = ty * 4;  // first LDS row this thread touches

    float acc[4][4] = {};

    #pragma unroll
    for (int r = 0; r < 10; ++r) {
        const float* rp = &tile[(rbase + r) * LDS_W + lx];
        const float4 a  = *(const float4*)(rp);
        const float4 b  = *(const float4*)(rp + 4);
        const float4 c4 = *(const float4*)(rp + 8);
        // LDS col (lx+t) holds global x = bx+lx+t-4; output col ox+c tap kx
        // needs global x = bx+lx+c+kx-3 -> t = c+kx+1.
        const float row[12] = { a.x, a.y, a.z, a.w,
                                b.x, b.y, b.z, b.w,
                                c4.x, c4.y, c4.z, c4.w };
        #pragma unroll
        for (int j = 0; j < 4; ++j) {
            const int ky = r - j;
            if (ky >= 0 && ky < 7) {
                #pragma unroll
                for (int kx = 0; kx < 7; ++kx) {
                    const float wv = w[ky * 7 + kx];
                    #pragma unroll
                    for (int c = 0; c < 4; ++c)
                        acc[j][c] = fmaf(row[c + kx + 1], wv, acc[j][c]);
                }
            }
        }
    }

    // ---- store: 4 rows of float4 per thread ----
    float* o = out + (size_t)n * (IMG_W * IMG_H);
    #pragma unroll
    for (int j = 0; j < 4; ++j) {
        float4 v = make_float4(acc[j][0], acc[j][1], acc[j][2], acc[j][3]);
        *(float4*)&o[(size_t)(by + rbase + j) * IMG_W + bx + lx] = v;
    }
}

extern "C" void kernel_launch(void* const* d_in, const int* in_sizes, int n_in,
                              void* d_out, int out_size, void* d_ws, size_t ws_size,
                              hipStream_t stream)
{
    const float* x   = (const float*)d_in[0];
    const float* wgt = (const float*)d_in[1];
    float* out       = (float*)d_out;

    dim3 grid(IMG_W / TW, IMG_H / TH, NIMG);   // 2 x 32 x 64 = 4096 blocks
    conv7x7_kernel<<<grid, 256, 0, stream>>>(x, wgt, out);
}